// Round 1
// baseline (1991.131 us; speedup 1.0000x reference)
//
#include <hip/hip_runtime.h>
#include <hip/hip_bf16.h>

#define D 1024
#define H 8
#define S 2048
#define DFF 3072
#define EPS 1e-5f

typedef __attribute__((ext_vector_type(8))) short short8;   // 8 bf16 in 4 VGPRs
typedef __attribute__((ext_vector_type(4))) float float4v;  // MFMA acc

// GEMM flags
#define F_OUT_BF16 1
#define F_ACCUM    2
#define F_RELU     4
#define F_BIAS_COL 8
#define F_BIAS_ROW 16

// ---------------------------------------------------------------------------
// Generic C = alpha*A.Bt^T (+bias)(+relu) GEMM.
// A: [M,K] bf16 row-major.  Bt: [N,K] bf16 row-major (i.e. B transposed).
// Cout: [M,N] bf16 or fp32.  M%128==0, N%128==0, K%32==0 required.
// Block 256 thr = 4 waves in 2x2, each wave does 64x64 via 4x4 mfma 16x16x32.
// ---------------------------------------------------------------------------
__global__ __launch_bounds__(256) void gemm_bt(
    const __hip_bfloat16* __restrict__ A,
    const __hip_bfloat16* __restrict__ Bt,
    void* __restrict__ Cout,
    const float* __restrict__ bias,
    int M, int N, int K, float alpha, int flags)
{
    __shared__ __align__(16) __hip_bfloat16 As[128 * 32];
    __shared__ __align__(16) __hip_bfloat16 Bs[128 * 32];

    const int t    = threadIdx.x;
    const int wave = t >> 6;
    const int lane = t & 63;
    const int lr   = lane & 15;     // row within 16x16 fragment
    const int lq   = lane >> 4;     // k-quad
    const int wm   = (wave >> 1) * 64;
    const int wn   = (wave & 1) * 64;
    const int m0   = blockIdx.y * 128;
    const int n0   = blockIdx.x * 128;

    // staging: 128 rows x 32 elems = 512 chunks of 16B; thread t does chunks t, t+256
    const __hip_bfloat16* Ap1 = A  + (long)(m0 + (t >> 2)) * K + (t & 3) * 8;
    const __hip_bfloat16* Ap2 = Ap1 + 64L * K;
    const __hip_bfloat16* Bp1 = Bt + (long)(n0 + (t >> 2)) * K + (t & 3) * 8;
    const __hip_bfloat16* Bp2 = Bp1 + 64L * K;

    float4v acc[4][4];
    const float4v vzero = {0.f, 0.f, 0.f, 0.f};
    #pragma unroll
    for (int i = 0; i < 4; i++)
        #pragma unroll
        for (int j = 0; j < 4; j++) acc[i][j] = vzero;

    for (int k0 = 0; k0 < K; k0 += 32) {
        uint4 a1 = *(const uint4*)(Ap1 + k0);
        uint4 a2 = *(const uint4*)(Ap2 + k0);
        uint4 b1 = *(const uint4*)(Bp1 + k0);
        uint4 b2 = *(const uint4*)(Bp2 + k0);
        __syncthreads();
        ((uint4*)As)[t]       = a1;
        ((uint4*)As)[t + 256] = a2;
        ((uint4*)Bs)[t]       = b1;
        ((uint4*)Bs)[t + 256] = b2;
        __syncthreads();

        short8 af[4], bf[4];
        #pragma unroll
        for (int i = 0; i < 4; i++)
            af[i] = *(const short8*)&As[(wm + i * 16 + lr) * 32 + lq * 8];
        #pragma unroll
        for (int i = 0; i < 4; i++)
            bf[i] = *(const short8*)&Bs[(wn + i * 16 + lr) * 32 + lq * 8];

        #pragma unroll
        for (int mi = 0; mi < 4; mi++)
            #pragma unroll
            for (int ni = 0; ni < 4; ni++)
                acc[mi][ni] = __builtin_amdgcn_mfma_f32_16x16x32_bf16(
                    af[mi], bf[ni], acc[mi][ni], 0, 0, 0);
    }

    // epilogue: lane l, reg r -> row = 4*lq + r, col = lr (within 16x16 tile)
    #pragma unroll
    for (int mi = 0; mi < 4; mi++) {
        #pragma unroll
        for (int r = 0; r < 4; r++) {
            const int row = m0 + wm + mi * 16 + lq * 4 + r;
            const float brow = (flags & F_BIAS_ROW) ? bias[row] : 0.f;
            #pragma unroll
            for (int ni = 0; ni < 4; ni++) {
                const int col = n0 + wn + ni * 16 + lr;
                float v = acc[mi][ni][r] * alpha + brow;
                if (flags & F_BIAS_COL) v += bias[col];
                if (flags & F_RELU) v = fmaxf(v, 0.f);
                const long idx = (long)row * N + col;
                if (flags & F_OUT_BF16) {
                    ((__hip_bfloat16*)Cout)[idx] = __float2bfloat16(v);
                } else {
                    float* C = (float*)Cout;
                    if (flags & F_ACCUM) C[idx] += v;
                    else                 C[idx] = v;
                }
            }
        }
    }
}

// ---------------------------------------------------------------------------
// fp32 [R,C] -> bf16 [C,R] transpose+cast, batched via blockIdx.z
// ---------------------------------------------------------------------------
__global__ __launch_bounds__(256) void transpose_cast(
    const float* __restrict__ in, __hip_bfloat16* __restrict__ out, int R, int C)
{
    __shared__ float tile[32][33];
    const long boff = (long)blockIdx.z * R * C;
    const int c0 = blockIdx.x * 32, r0 = blockIdx.y * 32;
    const int tx = threadIdx.x & 31, ty = threadIdx.x >> 5;
    #pragma unroll
    for (int i = ty; i < 32; i += 8)
        tile[i][tx] = in[boff + (long)(r0 + i) * C + c0 + tx];
    __syncthreads();
    #pragma unroll
    for (int i = ty; i < 32; i += 8)
        out[boff + (long)(c0 + i) * R + r0 + tx] = __float2bfloat16(tile[tx][i]);
}

// ---------------------------------------------------------------------------
// x = emb[tokens] + sinusoidal PE ; writes fp32 and bf16 copies
// ---------------------------------------------------------------------------
__global__ __launch_bounds__(256) void embed_pos(
    const int* __restrict__ tokens, const float* __restrict__ emb,
    float* __restrict__ xf, __hip_bfloat16* __restrict__ xb)
{
    const int s = blockIdx.x;
    const int tok = tokens[s];
    for (int d = threadIdx.x; d < D; d += 256) {
        const float e = emb[(long)tok * D + d];
        const float expo = (float)((d >> 1) << 1) / (float)D;
        const float angle = (float)s * powf(10000.f, -expo);
        const float pe = (d & 1) ? cosf(angle) : sinf(angle);
        const float v = e + pe;
        xf[(long)s * D + d] = v;
        xb[(long)s * D + d] = __float2bfloat16(v);
    }
}

// ---------------------------------------------------------------------------
// in-place row softmax over bf16 [rows, S] buffer; one block per row
// ---------------------------------------------------------------------------
__global__ __launch_bounds__(256) void softmax_rows(__hip_bfloat16* __restrict__ Sc)
{
    __hip_bfloat16* p = Sc + (long)blockIdx.x * S;
    const int t = threadIdx.x;
    const int wave = t >> 6, lane = t & 63;
    __shared__ float wred[4], wsum[4];

    float v[8];
    float mx = -1e30f;
    #pragma unroll
    for (int j = 0; j < 8; j++) {
        v[j] = __bfloat162float(p[t + j * 256]);
        mx = fmaxf(mx, v[j]);
    }
    #pragma unroll
    for (int off = 32; off; off >>= 1) mx = fmaxf(mx, __shfl_down(mx, off));
    if (lane == 0) wred[wave] = mx;
    __syncthreads();
    mx = fmaxf(fmaxf(wred[0], wred[1]), fmaxf(wred[2], wred[3]));

    float sum = 0.f;
    #pragma unroll
    for (int j = 0; j < 8; j++) { v[j] = expf(v[j] - mx); sum += v[j]; }
    #pragma unroll
    for (int off = 32; off; off >>= 1) sum += __shfl_down(sum, off);
    if (lane == 0) wsum[wave] = sum;
    __syncthreads();
    sum = wsum[0] + wsum[1] + wsum[2] + wsum[3];

    const float inv = 1.f / sum;
    #pragma unroll
    for (int j = 0; j < 8; j++) p[t + j * 256] = __float2bfloat16(v[j] * inv);
}

// ---------------------------------------------------------------------------
// z = mha + x ; accumulate global sum & sumsq into stats[0..1] (pre-zeroed)
// ---------------------------------------------------------------------------
__global__ __launch_bounds__(256) void residual_stats(
    const float* __restrict__ mha, const float* __restrict__ xf,
    float* __restrict__ z, float* __restrict__ stats)
{
    const long i0 = (long)blockIdx.x * 2048 + threadIdx.x;
    float s = 0.f, s2 = 0.f;
    #pragma unroll
    for (int j = 0; j < 8; j++) {
        const long i = i0 + j * 256;
        const float v = mha[i] + xf[i];
        z[i] = v;
        s += v; s2 += v * v;
    }
    #pragma unroll
    for (int off = 32; off; off >>= 1) { s += __shfl_down(s, off); s2 += __shfl_down(s2, off); }
    const int wave = threadIdx.x >> 6, lane = threadIdx.x & 63;
    __shared__ float ws1[4], ws2[4];
    if (lane == 0) { ws1[wave] = s; ws2[wave] = s2; }
    __syncthreads();
    if (threadIdx.x == 0) {
        atomicAdd(&stats[0], ws1[0] + ws1[1] + ws1[2] + ws1[3]);
        atomicAdd(&stats[1], ws2[0] + ws2[1] + ws2[2] + ws2[3]);
    }
}

// zn = (z - mean) * rsqrt(var + eps), cast to bf16
__global__ __launch_bounds__(256) void ln_cast(
    const float* __restrict__ z, const float* __restrict__ stats,
    __hip_bfloat16* __restrict__ zn)
{
    const float invN = 1.f / (float)(S * D);
    const float mean = stats[0] * invN;
    const float var  = stats[1] * invN - mean * mean;
    const float rs   = rsqrtf(var + EPS);
    const long i0 = (long)blockIdx.x * 2048 + threadIdx.x;
    #pragma unroll
    for (int j = 0; j < 8; j++) {
        const long i = i0 + j * 256;
        zn[i] = __float2bfloat16((z[i] - mean) * rs);
    }
}

// ---------------------------------------------------------------------------
extern "C" void kernel_launch(void* const* d_in, const int* in_sizes, int n_in,
                              void* d_out, int out_size, void* d_ws, size_t ws_size,
                              hipStream_t stream)
{
    const int*   tokens = (const int*)  d_in[0];
    const float* emb    = (const float*)d_in[1];
    const float* Wq     = (const float*)d_in[2];
    const float* bq     = (const float*)d_in[3];
    const float* Wk     = (const float*)d_in[4];
    const float* bk     = (const float*)d_in[5];
    const float* Wv     = (const float*)d_in[6];
    const float* bv     = (const float*)d_in[7];
    const float* W1     = (const float*)d_in[8];
    const float* b1     = (const float*)d_in[9];
    const float* W2     = (const float*)d_in[10];
    const float* b2     = (const float*)d_in[11];
    float* out = (float*)d_out;

    char* w = (char*)d_ws;
    // workspace layout (total ~130 MB)
    __hip_bfloat16* XB  = (__hip_bfloat16*)(w + 0);            // S*D bf16      4 MB
    float*          XF  = (float*)(w + 4194304);               // S*D f32       8 MB
    __hip_bfloat16* WQT = (__hip_bfloat16*)(w + 12582912);     // H*D*D bf16   16 MB
    __hip_bfloat16* WKT = (__hip_bfloat16*)(w + 29360128);
    __hip_bfloat16* WVT = (__hip_bfloat16*)(w + 46137344);
    __hip_bfloat16* W1T = (__hip_bfloat16*)(w + 62914560);     // DFF*D bf16    6 MB
    __hip_bfloat16* W2T = (__hip_bfloat16*)(w + 69206016);     // D*DFF bf16    6 MB
    __hip_bfloat16* QH  = (__hip_bfloat16*)(w + 75497472);     // S*D bf16
    __hip_bfloat16* KH  = (__hip_bfloat16*)(w + 79691776);
    __hip_bfloat16* VTH = (__hip_bfloat16*)(w + 83886080);     // D*S bf16
    __hip_bfloat16* SC  = (__hip_bfloat16*)(w + 88080384);     // S*S bf16      8 MB
    float*          MHA = (float*)(w + 96468992);              // S*D f32       8 MB
    float*          Z   = (float*)(w + 104857600);             // S*D f32       8 MB
    __hip_bfloat16* ZN  = (__hip_bfloat16*)(w + 113246208);    // S*D bf16
    __hip_bfloat16* FFH = (__hip_bfloat16*)(w + 117440512);    // S*DFF bf16   12 MB
    float*          STATS = (float*)(w + 130023424);

    hipMemsetAsync(STATS, 0, 256, stream);
    hipMemsetAsync(MHA, 0, (size_t)S * D * sizeof(float), stream);

    embed_pos<<<S, 256, 0, stream>>>(tokens, emb, XF, XB);

    // weight transpose+cast:  Wq/Wk/Wv [H,D,D] -> [H,(e),(d)] bf16
    transpose_cast<<<dim3(32, 32, H), 256, 0, stream>>>(Wq, WQT, D, D);
    transpose_cast<<<dim3(32, 32, H), 256, 0, stream>>>(Wk, WKT, D, D);
    transpose_cast<<<dim3(32, 32, H), 256, 0, stream>>>(Wv, WVT, D, D);
    transpose_cast<<<dim3(96, 32, 1), 256, 0, stream>>>(W1, W1T, D, DFF);  // -> [DFF,D]
    transpose_cast<<<dim3(32, 96, 1), 256, 0, stream>>>(W2, W2T, DFF, D);  // -> [D,DFF]

    const float inv_sqrt_d = 0.03125f;  // 1/sqrt(1024)

    for (int h = 0; h < H; h++) {
        // Q_h = x @ Wq[h] + bq[h]   [S,D] bf16
        gemm_bt<<<dim3(D / 128, S / 128), 256, 0, stream>>>(
            XB, WQT + (long)h * D * D, QH, bq + h * D, S, D, D, 1.f,
            F_OUT_BF16 | F_BIAS_COL);
        // K_h
        gemm_bt<<<dim3(D / 128, S / 128), 256, 0, stream>>>(
            XB, WKT + (long)h * D * D, KH, bk + h * D, S, D, D, 1.f,
            F_OUT_BF16 | F_BIAS_COL);
        // Vt_h[e][t] = sum_d WvT[h][e][d] * x[t][d] + bv[h][e]   [D,S] bf16
        gemm_bt<<<dim3(S / 128, D / 128), 256, 0, stream>>>(
            WVT + (long)h * D * D, XB, VTH, bv + h * D, D, S, D, 1.f,
            F_OUT_BF16 | F_BIAS_ROW);
        // scores = Q K^T / sqrt(D)   [S,S] bf16
        gemm_bt<<<dim3(S / 128, S / 128), 256, 0, stream>>>(
            QH, KH, SC, (const float*)nullptr, S, S, D, inv_sqrt_d, F_OUT_BF16);
        softmax_rows<<<S, 256, 0, stream>>>(SC);
        // mha += P @ V_h   (fp32 accumulate)
        gemm_bt<<<dim3(D / 128, S / 128), 256, 0, stream>>>(
            SC, VTH, MHA, (const float*)nullptr, S, D, S, 1.f, F_ACCUM);
    }

    residual_stats<<<(S * D) / 2048, 256, 0, stream>>>(MHA, XF, Z, STATS);
    ln_cast<<<(S * D) / 2048, 256, 0, stream>>>(Z, STATS, ZN);

    // FF1: relu(zn @ W1 + b1)  [S,DFF] bf16
    gemm_bt<<<dim3(DFF / 128, S / 128), 256, 0, stream>>>(
        ZN, W1T, FFH, b1, S, DFF, D, 1.f, F_OUT_BF16 | F_BIAS_COL | F_RELU);
    // FF2: out = h @ W2 + b2   [S,D] fp32 -> d_out
    gemm_bt<<<dim3(D / 128, S / 128), 256, 0, stream>>>(
        FFH, W2T, out, b2, S, D, DFF, 1.f, F_BIAS_COL);
}

// Round 2
// 956.699 us; speedup vs baseline: 2.0813x; 2.0813x over previous
//
#include <hip/hip_runtime.h>
#include <hip/hip_bf16.h>

#define D 1024
#define H 8
#define S 2048
#define DFF 3072
#define HD 8192
#define EPS 1e-5f
#define HB 4   // heads per attention pass (SC buffer = HB * 8 MB)

typedef __attribute__((ext_vector_type(8))) short short8;   // 8 bf16 in 4 VGPRs
typedef __attribute__((ext_vector_type(4))) float float4v;  // MFMA acc

// GEMM flags
#define F_OUT_BF16 1
#define F_ACCUM    2   // fp32 atomicAdd into C
#define F_RELU     4
#define F_BIAS_COL 8
#define F_BIAS_ROW 16
#define F_SPLITK   32  // bias applied only when blockIdx.z == 0

__device__ __forceinline__ void async16(void* lds, const void* g) {
    __builtin_amdgcn_global_load_lds(
        (const __attribute__((address_space(1))) unsigned int*)g,
        (__attribute__((address_space(3))) unsigned int*)lds, 16, 0, 0);
}

// ---------------------------------------------------------------------------
// C = alpha*A.Bt^T (+bias)(+relu).  A:[M,K] bf16 lda; Bt:[N,K] bf16 ldb.
// Per-z (blockIdx.z) element offsets sA/sB/sC/sBias allow head-batching and
// split-K.  Block 256 = 4 waves 2x2, wave does 64x64 via 4x4 mfma 16x16x32.
// Staging via global_load_lds width-16 (m97 structure).
// ---------------------------------------------------------------------------
__global__ __launch_bounds__(256) void gemm_bt(
    const __hip_bfloat16* __restrict__ A,
    const __hip_bfloat16* __restrict__ Bt,
    void* __restrict__ Cout,
    const float* __restrict__ bias,
    int M, int N, int K,
    int lda, int ldb, int ldc,
    long sA, long sB, long sC, int sBias,
    float alpha, int flags)
{
    __shared__ __align__(16) __hip_bfloat16 As[128 * 32];
    __shared__ __align__(16) __hip_bfloat16 Bs[128 * 32];

    const int z = blockIdx.z;
    A  += (long)z * sA;
    Bt += (long)z * sB;
    const bool bon = bias && (!(flags & F_SPLITK) || z == 0);
    const float* bp = bon ? bias + (long)z * sBias : nullptr;

    const int t    = threadIdx.x;
    const int wave = t >> 6;
    const int lane = t & 63;
    const int lr   = lane & 15;     // row within 16x16 fragment
    const int lq   = lane >> 4;     // k-quad
    const int wm   = (wave >> 1) * 64;
    const int wn   = (wave & 1) * 64;
    const int m0   = blockIdx.y * 128;
    const int n0   = blockIdx.x * 128;

    // staging: each tile is 128 rows x 32 elems = 512 x 16B; thread t owns
    // chunks t and t+256 (lane-contiguous LDS dest, required by global_load_lds)
    const __hip_bfloat16* Ap1 = A  + (long)(m0 + (t >> 2)) * lda + (t & 3) * 8;
    const __hip_bfloat16* Ap2 = Ap1 + 64L * lda;
    const __hip_bfloat16* Bp1 = Bt + (long)(n0 + (t >> 2)) * ldb + (t & 3) * 8;
    const __hip_bfloat16* Bp2 = Bp1 + 64L * ldb;
    uint4* dA1 = (uint4*)As + t;
    uint4* dA2 = (uint4*)As + t + 256;
    uint4* dB1 = (uint4*)Bs + t;
    uint4* dB2 = (uint4*)Bs + t + 256;

    float4v acc[4][4];
    const float4v vzero = {0.f, 0.f, 0.f, 0.f};
    #pragma unroll
    for (int i = 0; i < 4; i++)
        #pragma unroll
        for (int j = 0; j < 4; j++) acc[i][j] = vzero;

    for (int k0 = 0; k0 < K; k0 += 32) {
        __syncthreads();            // prev iter's ds_reads complete
        async16(dA1, Ap1);
        async16(dA2, Ap2);
        async16(dB1, Bp1);
        async16(dB2, Bp2);
        Ap1 += 32; Ap2 += 32; Bp1 += 32; Bp2 += 32;
        __syncthreads();            // vmcnt(0) drain: tiles ready

        short8 af[4], bf[4];
        #pragma unroll
        for (int i = 0; i < 4; i++)
            af[i] = *(const short8*)&As[(wm + i * 16 + lr) * 32 + lq * 8];
        #pragma unroll
        for (int i = 0; i < 4; i++)
            bf[i] = *(const short8*)&Bs[(wn + i * 16 + lr) * 32 + lq * 8];

        #pragma unroll
        for (int mi = 0; mi < 4; mi++)
            #pragma unroll
            for (int ni = 0; ni < 4; ni++)
                acc[mi][ni] = __builtin_amdgcn_mfma_f32_16x16x32_bf16(
                    af[mi], bf[ni], acc[mi][ni], 0, 0, 0);
    }

    __hip_bfloat16* Cb = (__hip_bfloat16*)Cout + (long)z * sC;
    float*          Cf = (float*)Cout + (long)z * sC;

    // epilogue: lane, reg r -> row = 4*lq + r, col = lr (within 16x16 tile)
    #pragma unroll
    for (int mi = 0; mi < 4; mi++) {
        #pragma unroll
        for (int r = 0; r < 4; r++) {
            const int row = m0 + wm + mi * 16 + lq * 4 + r;
            const float brow = (bon && (flags & F_BIAS_ROW)) ? bp[row] : 0.f;
            #pragma unroll
            for (int ni = 0; ni < 4; ni++) {
                const int col = n0 + wn + ni * 16 + lr;
                float v = acc[mi][ni][r] * alpha + brow;
                if (bon && (flags & F_BIAS_COL)) v += bp[col];
                if (flags & F_RELU) v = fmaxf(v, 0.f);
                const long idx = (long)row * ldc + col;
                if (flags & F_OUT_BF16) {
                    Cb[idx] = __float2bfloat16(v);
                } else if (flags & F_ACCUM) {
                    atomicAdd(&Cf[idx], v);
                } else {
                    Cf[idx] = v;
                }
            }
        }
    }
}

// ---------------------------------------------------------------------------
// fp32 [R,C] -> bf16 [C,R] transpose+cast, batched via blockIdx.z
// ---------------------------------------------------------------------------
__global__ __launch_bounds__(256) void transpose_cast(
    const float* __restrict__ in, __hip_bfloat16* __restrict__ out, int R, int C)
{
    __shared__ float tile[32][33];
    const long boff = (long)blockIdx.z * R * C;
    const int c0 = blockIdx.x * 32, r0 = blockIdx.y * 32;
    const int tx = threadIdx.x & 31, ty = threadIdx.x >> 5;
    #pragma unroll
    for (int i = ty; i < 32; i += 8)
        tile[i][tx] = in[boff + (long)(r0 + i) * C + c0 + tx];
    __syncthreads();
    #pragma unroll
    for (int i = ty; i < 32; i += 8)
        out[boff + (long)(c0 + i) * R + r0 + tx] = __float2bfloat16(tile[tx][i]);
}

// ---------------------------------------------------------------------------
// x = emb[tokens] + sinusoidal PE ; writes fp32 and bf16 copies
// ---------------------------------------------------------------------------
__global__ __launch_bounds__(256) void embed_pos(
    const int* __restrict__ tokens, const float* __restrict__ emb,
    float* __restrict__ xf, __hip_bfloat16* __restrict__ xb)
{
    const int s = blockIdx.x;
    const int tok = tokens[s];
    for (int d = threadIdx.x; d < D; d += 256) {
        const float e = emb[(long)tok * D + d];
        const float expo = (float)((d >> 1) << 1) / (float)D;
        const float angle = (float)s * powf(10000.f, -expo);
        const float pe = (d & 1) ? cosf(angle) : sinf(angle);
        const float v = e + pe;
        xf[(long)s * D + d] = v;
        xb[(long)s * D + d] = __float2bfloat16(v);
    }
}

// ---------------------------------------------------------------------------
// in-place row softmax over bf16 [rows, S]; one block per row
// ---------------------------------------------------------------------------
__global__ __launch_bounds__(256) void softmax_rows(__hip_bfloat16* __restrict__ Sc)
{
    __hip_bfloat16* p = Sc + (long)blockIdx.x * S;
    const int t = threadIdx.x;
    const int wave = t >> 6, lane = t & 63;
    __shared__ float wred[4], wsum[4];

    float v[8];
    float mx = -1e30f;
    #pragma unroll
    for (int j = 0; j < 8; j++) {
        v[j] = __bfloat162float(p[t + j * 256]);
        mx = fmaxf(mx, v[j]);
    }
    #pragma unroll
    for (int off = 32; off; off >>= 1) mx = fmaxf(mx, __shfl_down(mx, off));
    if (lane == 0) wred[wave] = mx;
    __syncthreads();
    mx = fmaxf(fmaxf(wred[0], wred[1]), fmaxf(wred[2], wred[3]));

    float sum = 0.f;
    #pragma unroll
    for (int j = 0; j < 8; j++) { v[j] = expf(v[j] - mx); sum += v[j]; }
    #pragma unroll
    for (int off = 32; off; off >>= 1) sum += __shfl_down(sum, off);
    if (lane == 0) wsum[wave] = sum;
    __syncthreads();
    sum = wsum[0] + wsum[1] + wsum[2] + wsum[3];

    const float inv = 1.f / sum;
    #pragma unroll
    for (int j = 0; j < 8; j++) p[t + j * 256] = __float2bfloat16(v[j] * inv);
}

// ---------------------------------------------------------------------------
// z = mha + x ; accumulate global sum & sumsq into stats[0..1] (pre-zeroed)
// ---------------------------------------------------------------------------
__global__ __launch_bounds__(256) void residual_stats(
    const float* __restrict__ mha, const float* __restrict__ xf,
    float* __restrict__ z, float* __restrict__ stats)
{
    const long i0 = (long)blockIdx.x * 2048 + threadIdx.x;
    float s = 0.f, s2 = 0.f;
    #pragma unroll
    for (int j = 0; j < 8; j++) {
        const long i = i0 + j * 256;
        const float v = mha[i] + xf[i];
        z[i] = v;
        s += v; s2 += v * v;
    }
    #pragma unroll
    for (int off = 32; off; off >>= 1) { s += __shfl_down(s, off); s2 += __shfl_down(s2, off); }
    const int wave = threadIdx.x >> 6, lane = threadIdx.x & 63;
    __shared__ float ws1[4], ws2[4];
    if (lane == 0) { ws1[wave] = s; ws2[wave] = s2; }
    __syncthreads();
    if (threadIdx.x == 0) {
        atomicAdd(&stats[0], ws1[0] + ws1[1] + ws1[2] + ws1[3]);
        atomicAdd(&stats[1], ws2[0] + ws2[1] + ws2[2] + ws2[3]);
    }
}

// zn = (z - mean) * rsqrt(var + eps), cast to bf16
__global__ __launch_bounds__(256) void ln_cast(
    const float* __restrict__ z, const float* __restrict__ stats,
    __hip_bfloat16* __restrict__ zn)
{
    const float invN = 1.f / (float)(S * D);
    const float mean = stats[0] * invN;
    const float var  = stats[1] * invN - mean * mean;
    const float rs   = rsqrtf(var + EPS);
    const long i0 = (long)blockIdx.x * 2048 + threadIdx.x;
    #pragma unroll
    for (int j = 0; j < 8; j++) {
        const long i = i0 + j * 256;
        zn[i] = __float2bfloat16((z[i] - mean) * rs);
    }
}

// ---------------------------------------------------------------------------
extern "C" void kernel_launch(void* const* d_in, const int* in_sizes, int n_in,
                              void* d_out, int out_size, void* d_ws, size_t ws_size,
                              hipStream_t stream)
{
    const int*   tokens = (const int*)  d_in[0];
    const float* emb    = (const float*)d_in[1];
    const float* Wq     = (const float*)d_in[2];
    const float* bq     = (const float*)d_in[3];
    const float* Wk     = (const float*)d_in[4];
    const float* bk     = (const float*)d_in[5];
    const float* Wv     = (const float*)d_in[6];
    const float* bv     = (const float*)d_in[7];
    const float* W1     = (const float*)d_in[8];
    const float* b1     = (const float*)d_in[9];
    const float* W2     = (const float*)d_in[10];
    const float* b2     = (const float*)d_in[11];
    float* out = (float*)d_out;

    char* w = (char*)d_ws;
    const long MB = 1 << 20;
    // layout with aliasing (total 168 MB + stats page):
    //  0: XB(4) | 4: XF(8) | 12: WQT(16)/WKT@28(16)/WVT@44(16) -> after QKV
    //  gemms: SC@12(32), MHA@44(8,f32), Z@52(8,f32)
    //  60: W1T(6) | 66: W2T(6) | 72: Q(32) -> after attn: ZN@72(4), FFH@76(12)
    //  104: K(32) | 136: VT(32) | 168: STATS
    __hip_bfloat16* XB  = (__hip_bfloat16*)(w + 0 * MB);
    float*          XF  = (float*)(w + 4 * MB);
    __hip_bfloat16* WQT = (__hip_bfloat16*)(w + 12 * MB);
    __hip_bfloat16* WKT = (__hip_bfloat16*)(w + 28 * MB);
    __hip_bfloat16* WVT = (__hip_bfloat16*)(w + 44 * MB);
    __hip_bfloat16* SC  = (__hip_bfloat16*)(w + 12 * MB);   // alias WQT/WKT
    float*          MHA = (float*)(w + 44 * MB);            // alias WVT
    float*          Z   = (float*)(w + 52 * MB);            // alias WVT tail
    __hip_bfloat16* W1T = (__hip_bfloat16*)(w + 60 * MB);
    __hip_bfloat16* W2T = (__hip_bfloat16*)(w + 66 * MB);
    __hip_bfloat16* Q   = (__hip_bfloat16*)(w + 72 * MB);
    __hip_bfloat16* ZN  = (__hip_bfloat16*)(w + 72 * MB);   // alias Q (dead)
    __hip_bfloat16* FFH = (__hip_bfloat16*)(w + 76 * MB);   // alias Q (dead)
    __hip_bfloat16* Kb  = (__hip_bfloat16*)(w + 104 * MB);
    __hip_bfloat16* VT  = (__hip_bfloat16*)(w + 136 * MB);
    float*          STATS = (float*)(w + 168 * MB);

    hipMemsetAsync(STATS, 0, 256, stream);

    embed_pos<<<S, 256, 0, stream>>>(tokens, emb, XF, XB);

    // weight transpose+cast
    transpose_cast<<<dim3(32, 32, H), 256, 0, stream>>>(Wq, WQT, D, D);
    transpose_cast<<<dim3(32, 32, H), 256, 0, stream>>>(Wk, WKT, D, D);
    transpose_cast<<<dim3(32, 32, H), 256, 0, stream>>>(Wv, WVT, D, D);
    transpose_cast<<<dim3(96, 32, 1), 256, 0, stream>>>(W1, W1T, D, DFF);  // -> [DFF,D]
    transpose_cast<<<dim3(32, 96, 1), 256, 0, stream>>>(W2, W2T, DFF, D);  // -> [D,DFF]

    // Q = x @ Wq^T(all heads) + bq    [S, HD]
    gemm_bt<<<dim3(HD / 128, S / 128), 256, 0, stream>>>(
        XB, WQT, Q, bq, S, HD, D, D, D, HD, 0, 0, 0, 0, 1.f,
        F_OUT_BF16 | F_BIAS_COL);
    // K = x @ Wk^T + bk               [S, HD]
    gemm_bt<<<dim3(HD / 128, S / 128), 256, 0, stream>>>(
        XB, WKT, Kb, bk, S, HD, D, D, D, HD, 0, 0, 0, 0, 1.f,
        F_OUT_BF16 | F_BIAS_COL);
    // VT[h] = Wv[h]^T @ x^T + bv[h]   [H][D, S]  (batched over z)
    gemm_bt<<<dim3(S / 128, D / 128, H), 256, 0, stream>>>(
        WVT, XB, VT, bv, D, S, D, D, D, S,
        (long)D * D, 0, (long)D * S, D, 1.f,
        F_OUT_BF16 | F_BIAS_ROW);

    // MHA accumulator (zero AFTER VT gemm: aliases WVT)
    hipMemsetAsync(MHA, 0, (size_t)S * D * sizeof(float), stream);

    const float inv_sqrt_d = 0.03125f;  // 1/sqrt(1024)

    for (int g = 0; g < H / HB; g++) {
        // scores[z] = Q_h K_h^T / sqrt(D)   [S,S] bf16, h = g*HB+z
        gemm_bt<<<dim3(S / 128, S / 128, HB), 256, 0, stream>>>(
            Q + (long)g * HB * D, Kb + (long)g * HB * D, SC,
            (const float*)nullptr, S, S, D, HD, HD, S,
            D, D, (long)S * S, 0, inv_sqrt_d, F_OUT_BF16);
        softmax_rows<<<HB * S, 256, 0, stream>>>(SC);
        // MHA += P_h @ V_h   (fp32 atomic accumulate across heads)
        gemm_bt<<<dim3(D / 128, S / 128, HB), 256, 0, stream>>>(
            SC, VT + (long)g * HB * D * S, MHA,
            (const float*)nullptr, S, D, S, S, S, D,
            (long)S * S, (long)D * S, 0, 0, 1.f, F_ACCUM);
    }

    residual_stats<<<(S * D) / 2048, 256, 0, stream>>>(MHA, XF, Z, STATS);
    ln_cast<<<(S * D) / 2048, 256, 0, stream>>>(Z, STATS, ZN);

    // FF1: relu(zn @ W1 + b1)  [S,DFF] bf16
    gemm_bt<<<dim3(DFF / 128, S / 128), 256, 0, stream>>>(
        ZN, W1T, FFH, b1, S, DFF, D, D, D, DFF, 0, 0, 0, 0, 1.f,
        F_OUT_BF16 | F_BIAS_COL | F_RELU);
    // FF2: out = h @ W2 + b2  split-K=4, fp32 atomic into zeroed d_out
    hipMemsetAsync(out, 0, (size_t)S * D * sizeof(float), stream);
    gemm_bt<<<dim3(D / 128, S / 128, 4), 256, 0, stream>>>(
        FFH, W2T, out, b2, S, D, DFF / 4, DFF, DFF, D,
        DFF / 4, DFF / 4, 0, 0, 1.f, F_ACCUM | F_BIAS_COL | F_SPLITK);
}